// Round 3
// baseline (266.400 us; speedup 1.0000x reference)
//
#include <hip/hip_runtime.h>
#include <stdint.h>

typedef unsigned short u16;
typedef unsigned int   u32;
typedef _Float16 f16;
typedef __attribute__((ext_vector_type(4))) float    f32x4;
typedef __attribute__((ext_vector_type(8))) _Float16 f16x8;
typedef __attribute__((ext_vector_type(4))) _Float16 f16x4;

#define DIM    1024
#define NROWS  8192
#define NLAYER 10

__device__ __forceinline__ void gl_lds16(const void* g, void* l) {
    __builtin_amdgcn_global_load_lds((const __attribute__((address_space(1))) u32*)g,
                                     (__attribute__((address_space(3))) u32*)l, 16, 0, 0);
}

// ---------- conversion: f32 -> f16 plane ----------
__global__ __launch_bounds__(256) void conv_weights(const float* __restrict__ W0,
                                                    const float* __restrict__ Wh,
                                                    f16* __restrict__ Wf) {
    int i = (blockIdx.x * 256 + threadIdx.x) * 4;   // covers 10*1024*1024
    const float* src = (i < 1048576) ? (W0 + i) : (Wh + (i - 1048576));
    float4 w = *(const float4*)src;
    f16x4 o;
    o.x = (f16)w.x; o.y = (f16)w.y; o.z = (f16)w.z; o.w = (f16)w.w;
    *(f16x4*)(Wf + i) = o;
}

__global__ __launch_bounds__(256) void conv_x(const float* __restrict__ x,
                                              f16* __restrict__ Af) {
    int i = (blockIdx.x * 256 + threadIdx.x) * 4;   // covers 8192*1024
    float4 w = *(const float4*)(x + i);
    f16x4 o;
    o.x = (f16)w.x; o.y = (f16)w.y; o.z = (f16)w.z; o.w = (f16)w.w;
    *(f16x4*)(Af + i) = o;
}

// ---------- fused layer: C = A(8192xK) * W^T + bias, sigmoid -> f16 ----------
// BM=256 BN=128 BK=64, 512 threads = 8 waves (4M x 2N), 64x64/wave, f16 MFMA.
// 3-slot LDS ring (144 KB), stage runs 2 K-tiles ahead, counted vmcnt(6) at
// each iteration entry (T4) -- never drain to 0 in steady state.
#define ABUF_B 0        // [256][64] f16 = 32 KB
#define BBUF_B 32768    // [128][64] f16 = 16 KB
#define BUFSZ  49152
#define NKT    16

__global__ __launch_bounds__(512, 2) void layer_gemm(
        const f16* __restrict__ A,
        const f16* __restrict__ Bg,
        const float* __restrict__ bias,
        f16* __restrict__ O) {
    __shared__ char lds[3 * BUFSZ];   // 144 KB

    // XCD-aware bijective swizzle: 256 blocks, 8 XCDs, 32/XCD
    int bid = blockIdx.x;
    int swz = (bid & 7) * 32 + (bid >> 3);
    int bn = swz & 7;    // 0..7
    int bm = swz >> 3;   // 0..31

    const int tid  = threadIdx.x;
    const int lane = tid & 63;
    const int wid  = tid >> 6;
    const int wr   = wid >> 1;   // 0..3
    const int wc   = wid & 1;    // 0..1

    // ---- staging: 48 chunks of 1KB (8 rows x 128B) per K-tile, 6 per wave ----
    // pre-swizzled global source; logical (row r, colbyte cb) at LDS r*128 + (cb ^ ((r&7)<<4))
    const int swcol = (((lane & 7) ^ ((lane >> 3) & 7)) << 4);
    const char* gsrc[6];
    u32 ldst[6];
    #pragma unroll
    for (int j = 0; j < 6; ++j) {
        int c = wid * 6 + j;
        if (c < 32) {                       // A chunks
            int grow = bm * 256 + c * 8 + (lane >> 3);
            gsrc[j] = (const char*)A + (size_t)grow * 2048 + swcol;
            ldst[j] = ABUF_B + c * 1024;
        } else {                            // B chunks
            int c2 = c - 32;
            int grow = bn * 128 + c2 * 8 + (lane >> 3);
            gsrc[j] = (const char*)Bg + (size_t)grow * 2048 + swcol;
            ldst[j] = BBUF_B + c2 * 1024;
        }
    }

    f32x4 acc[4][4];
    #pragma unroll
    for (int mf = 0; mf < 4; ++mf)
        #pragma unroll
        for (int nf = 0; nf < 4; ++nf)
            acc[mf][nf] = (f32x4){0.f, 0.f, 0.f, 0.f};

    // prologue: stage kt=0 -> slot0, kt=1 -> slot1 (12 loads in flight)
    #pragma unroll
    for (int j = 0; j < 6; ++j)
        gl_lds16(gsrc[j], lds + ldst[j]);
    #pragma unroll
    for (int j = 0; j < 6; ++j)
        gl_lds16(gsrc[j] + 128, lds + BUFSZ + ldst[j]);

    int cur = 0, nx2 = 2;
    for (int kt = 0; kt < NKT; ++kt) {
        // entry: own stage(kt) loads are the oldest 6 of <=18 outstanding
        if (kt < NKT - 1) asm volatile("s_waitcnt vmcnt(6)" ::: "memory");
        else              asm volatile("s_waitcnt vmcnt(0)" ::: "memory");
        __builtin_amdgcn_s_barrier();          // all waves' tile-kt loads landed
        __builtin_amdgcn_sched_barrier(0);     // pin: no LDS reads hoisted above

        // stage tile kt+2 into slot nx2 (last read in compute(kt-1), pre-barrier)
        if (kt < NKT - 2) {
            #pragma unroll
            for (int j = 0; j < 6; ++j)
                gl_lds16(gsrc[j] + (size_t)(kt + 2) * 128, lds + nx2 * BUFSZ + ldst[j]);
        }

        const char* base = lds + cur * BUFSZ;
        #pragma unroll
        for (int ks = 0; ks < 2; ++ks) {
            f16x8 a[4], b[4];
            const int cb = ks * 64 + ((lane >> 4) << 4);
            #pragma unroll
            for (int mf = 0; mf < 4; ++mf) {
                int r = wr * 64 + mf * 16 + (lane & 15);
                int byt = r * 128 + (cb ^ ((r & 7) << 4));
                a[mf] = *(const f16x8*)(base + ABUF_B + byt);
            }
            #pragma unroll
            for (int nf = 0; nf < 4; ++nf) {
                int r = wc * 64 + nf * 16 + (lane & 15);
                int byt = r * 128 + (cb ^ ((r & 7) << 4));
                b[nf] = *(const f16x8*)(base + BBUF_B + byt);
            }
            __builtin_amdgcn_s_setprio(1);
            #pragma unroll
            for (int mf = 0; mf < 4; ++mf)
                #pragma unroll
                for (int nf = 0; nf < 4; ++nf)
                    // swapped operands -> C^T fragment layout (lane holds 4 consecutive cols)
                    acc[mf][nf] = __builtin_amdgcn_mfma_f32_16x16x32_f16(b[nf], a[mf], acc[mf][nf], 0, 0, 0);
            __builtin_amdgcn_s_setprio(0);
        }
        cur = (cur == 2) ? 0 : cur + 1;
        nx2 = (nx2 == 2) ? 0 : nx2 + 1;
    }

    // ---- epilogue: bias + sigmoid -> f16, 8B vector stores ----
    // swapped layout: lane holds rows gm = mf*16+(lane&15), cols gn0..gn0+3
    #pragma unroll
    for (int nf = 0; nf < 4; ++nf) {
        int gn0 = bn * 128 + wc * 64 + nf * 16 + ((lane >> 4) << 2);
        f32x4 b4 = *(const f32x4*)(bias + gn0);
        #pragma unroll
        for (int mf = 0; mf < 4; ++mf) {
            int gm = bm * 256 + wr * 64 + mf * 16 + (lane & 15);
            f16x4 o;
            #pragma unroll
            for (int j = 0; j < 4; ++j) {
                float z = acc[mf][nf][j] + b4[j];
                o[j] = (f16)(1.0f / (1.0f + __expf(-z)));
            }
            *(f16x4*)(O + (size_t)gm * DIM + gn0) = o;
        }
    }
}

// ---------- output GEMV ----------
__global__ __launch_bounds__(256) void out_gemv(const f16* __restrict__ A,
                                                const float* __restrict__ Wout,
                                                const float* __restrict__ bout,
                                                float* __restrict__ out) {
    int wid  = threadIdx.x >> 6;
    int lane = threadIdx.x & 63;
    int row  = blockIdx.x * 4 + wid;
    const f16* p = A + (size_t)row * DIM + lane * 16;
    const float* pw = Wout + lane * 16;
    float s = 0.f;
    #pragma unroll
    for (int i = 0; i < 4; ++i) {
        f16x4 h4 = *(const f16x4*)(p + i * 4);
        float4 w4 = *(const float4*)(pw + i * 4);
        s += (float)h4.x * w4.x + (float)h4.y * w4.y + (float)h4.z * w4.z + (float)h4.w * w4.w;
    }
    #pragma unroll
    for (int off = 32; off > 0; off >>= 1)
        s += __shfl_down(s, off);
    if (lane == 0) out[row] = s + bout[0];
}

// ---------- launcher ----------
extern "C" void kernel_launch(void* const* d_in, const int* in_sizes, int n_in,
                              void* d_out, int out_size, void* d_ws, size_t ws_size,
                              hipStream_t stream) {
    const float* x    = (const float*)d_in[0];
    const float* W0   = (const float*)d_in[1];
    const float* b0   = (const float*)d_in[2];
    const float* Wh   = (const float*)d_in[3];
    const float* bh   = (const float*)d_in[4];
    const float* Wout = (const float*)d_in[5];
    const float* bout = (const float*)d_in[6];
    float* out = (float*)d_out;

    f16* ws = (f16*)d_ws;
    f16* Wf = ws;                                  // 10*1024*1024 f16 = 20 MB
    f16* A0 = Wf + (size_t)NLAYER * DIM * DIM;     // 8192*1024 f16 = 16 MB
    f16* A1 = A0 + (size_t)NROWS * DIM;            // 16 MB

    conv_weights<<<NLAYER * DIM * DIM / 1024, 256, 0, stream>>>(W0, Wh, Wf);
    conv_x<<<NROWS * DIM / 1024, 256, 0, stream>>>(x, A0);

    const f16* in = A0;
    f16* o = A1;
    for (int l = 0; l < NLAYER; ++l) {
        const float* bias = (l == 0) ? b0 : (bh + (size_t)(l - 1) * DIM);
        layer_gemm<<<256, 512, 0, stream>>>(in, Wf + (size_t)l * DIM * DIM, bias, o);
        f16* t = (f16*)in; in = o; o = t;
    }

    out_gemv<<<NROWS / 4, 256, 0, stream>>>(in, Wout, bout, out);
}

// Round 4
// 260.140 us; speedup vs baseline: 1.0241x; 1.0241x over previous
//
#include <hip/hip_runtime.h>
#include <stdint.h>

typedef unsigned short u16;
typedef unsigned int   u32;
typedef _Float16 f16;
typedef __attribute__((ext_vector_type(4))) float    f32x4;
typedef __attribute__((ext_vector_type(8))) _Float16 f16x8;
typedef __attribute__((ext_vector_type(4))) _Float16 f16x4;

#define DIM    1024
#define NROWS  8192
#define NLAYER 10

__device__ __forceinline__ void gl_lds16(const void* g, void* l) {
    __builtin_amdgcn_global_load_lds((const __attribute__((address_space(1))) u32*)g,
                                     (__attribute__((address_space(3))) u32*)l, 16, 0, 0);
}

// ---------- conversion: f32 -> f16 plane ----------
__global__ __launch_bounds__(256) void conv_weights(const float* __restrict__ W0,
                                                    const float* __restrict__ Wh,
                                                    f16* __restrict__ Wf) {
    int i = (blockIdx.x * 256 + threadIdx.x) * 4;   // covers 10*1024*1024
    const float* src = (i < 1048576) ? (W0 + i) : (Wh + (i - 1048576));
    float4 w = *(const float4*)src;
    f16x4 o;
    o.x = (f16)w.x; o.y = (f16)w.y; o.z = (f16)w.z; o.w = (f16)w.w;
    *(f16x4*)(Wf + i) = o;
}

__global__ __launch_bounds__(256) void conv_x(const float* __restrict__ x,
                                              f16* __restrict__ Af) {
    int i = (blockIdx.x * 256 + threadIdx.x) * 4;   // covers 8192*1024
    float4 w = *(const float4*)(x + i);
    f16x4 o;
    o.x = (f16)w.x; o.y = (f16)w.y; o.z = (f16)w.z; o.w = (f16)w.w;
    *(f16x4*)(Af + i) = o;
}

// ---------- fused layer: C = A(8192xK) * W^T + bias, sigmoid -> f16 ----------
// BM=256 BN=128 BK=64, 512 threads = 8 waves (4M x 2N), 64x64/wave, f16 MFMA.
// 3-slot LDS ring (144 KB), stage 2 tiles ahead, counted vmcnt(6) gate per tile.
// T3: each K-tile = 2 phases of {8 ds_read + 3 stage -> barrier -> lgkmcnt(0)
// -> setprio(1) -> 16 MFMA -> setprio(0) -> barrier}, sched_barrier(0)-pinned.
#define ABUF_B 0        // [256][64] f16 = 32 KB
#define BBUF_B 32768    // [128][64] f16 = 16 KB
#define BUFSZ  49152
#define NKT    16

__global__ __launch_bounds__(512, 2) void layer_gemm(
        const f16* __restrict__ A,
        const f16* __restrict__ Bg,
        const float* __restrict__ bias,
        f16* __restrict__ O) {
    __shared__ char lds[3 * BUFSZ];   // 144 KB

    // XCD-aware bijective swizzle: 256 blocks, 8 XCDs, 32/XCD
    int bid = blockIdx.x;
    int swz = (bid & 7) * 32 + (bid >> 3);
    int bn = swz & 7;    // 0..7
    int bm = swz >> 3;   // 0..31

    const int tid  = threadIdx.x;
    const int lane = tid & 63;
    const int wid  = tid >> 6;
    const int wr   = wid >> 1;   // 0..3
    const int wc   = wid & 1;    // 0..1

    // ---- staging: 48 chunks of 1KB (8 rows x 128B) per K-tile, 6 per wave ----
    // pre-swizzled global source; logical (row r, colbyte cb) at LDS r*128 + (cb ^ ((r&7)<<4))
    const int swcol = (((lane & 7) ^ ((lane >> 3) & 7)) << 4);
    const char* gsrc[6];
    u32 ldst[6];
    #pragma unroll
    for (int j = 0; j < 6; ++j) {
        int c = wid * 6 + j;
        if (c < 32) {                       // A chunks
            int grow = bm * 256 + c * 8 + (lane >> 3);
            gsrc[j] = (const char*)A + (size_t)grow * 2048 + swcol;
            ldst[j] = ABUF_B + c * 1024;
        } else {                            // B chunks
            int c2 = c - 32;
            int grow = bn * 128 + c2 * 8 + (lane >> 3);
            gsrc[j] = (const char*)Bg + (size_t)grow * 2048 + swcol;
            ldst[j] = BBUF_B + c2 * 1024;
        }
    }

    // precomputed LDS read byte-offsets (row swizzle r&7 == lane&7 for all frags)
    u32 aoff[2][4], boff[2][4];
    #pragma unroll
    for (int ks = 0; ks < 2; ++ks) {
        const int cb = ks * 64 + ((lane >> 4) << 4);
        #pragma unroll
        for (int mf = 0; mf < 4; ++mf) {
            int r = wr * 64 + mf * 16 + (lane & 15);
            aoff[ks][mf] = ABUF_B + r * 128 + (cb ^ ((r & 7) << 4));
        }
        #pragma unroll
        for (int nf = 0; nf < 4; ++nf) {
            int r = wc * 64 + nf * 16 + (lane & 15);
            boff[ks][nf] = BBUF_B + r * 128 + (cb ^ ((r & 7) << 4));
        }
    }

    f32x4 acc[4][4];
    #pragma unroll
    for (int mf = 0; mf < 4; ++mf)
        #pragma unroll
        for (int nf = 0; nf < 4; ++nf)
            acc[mf][nf] = (f32x4){0.f, 0.f, 0.f, 0.f};

    // prologue: stage kt=0 -> slot0, kt=1 -> slot1 (12 loads in flight)
    #pragma unroll
    for (int j = 0; j < 6; ++j)
        gl_lds16(gsrc[j], lds + ldst[j]);
    #pragma unroll
    for (int j = 0; j < 6; ++j)
        gl_lds16(gsrc[j] + 128, lds + BUFSZ + ldst[j]);

    // gate: tile 0 resident (tile 1's 6 loads stay in flight)
    asm volatile("s_waitcnt vmcnt(6)" ::: "memory");
    __builtin_amdgcn_s_barrier();
    __builtin_amdgcn_sched_barrier(0);

    int cur = 0, nx2 = 2;
    for (int kt = 0; kt < NKT; ++kt) {
        const char* base = lds + cur * BUFSZ;
        char* sdst = lds + nx2 * BUFSZ;

        // ================= phase 0 (ks=0) =================
        f16x8 a0[4], b0[4];
        #pragma unroll
        for (int mf = 0; mf < 4; ++mf) a0[mf] = *(const f16x8*)(base + aoff[0][mf]);
        #pragma unroll
        for (int nf = 0; nf < 4; ++nf) b0[nf] = *(const f16x8*)(base + boff[0][nf]);
        __builtin_amdgcn_sched_barrier(0);
        if (kt < NKT - 2) {
            #pragma unroll
            for (int j = 0; j < 3; ++j)
                gl_lds16(gsrc[j] + (size_t)(kt + 2) * 128, sdst + ldst[j]);
        }
        __builtin_amdgcn_sched_barrier(0);
        __builtin_amdgcn_s_barrier();
        asm volatile("s_waitcnt lgkmcnt(0)" ::: "memory");
        __builtin_amdgcn_sched_barrier(0);
        __builtin_amdgcn_s_setprio(1);
        #pragma unroll
        for (int mf = 0; mf < 4; ++mf)
            #pragma unroll
            for (int nf = 0; nf < 4; ++nf)
                // swapped operands -> C^T layout (lane holds 4 consecutive cols)
                acc[mf][nf] = __builtin_amdgcn_mfma_f32_16x16x32_f16(b0[nf], a0[mf], acc[mf][nf], 0, 0, 0);
        __builtin_amdgcn_s_setprio(0);
        __builtin_amdgcn_sched_barrier(0);
        __builtin_amdgcn_s_barrier();

        // ================= phase 1 (ks=1) =================
        f16x8 a1[4], b1[4];
        #pragma unroll
        for (int mf = 0; mf < 4; ++mf) a1[mf] = *(const f16x8*)(base + aoff[1][mf]);
        #pragma unroll
        for (int nf = 0; nf < 4; ++nf) b1[nf] = *(const f16x8*)(base + boff[1][nf]);
        __builtin_amdgcn_sched_barrier(0);
        if (kt < NKT - 2) {
            #pragma unroll
            for (int j = 3; j < 6; ++j)
                gl_lds16(gsrc[j] + (size_t)(kt + 2) * 128, sdst + ldst[j]);
        }
        __builtin_amdgcn_sched_barrier(0);
        __builtin_amdgcn_s_barrier();
        asm volatile("s_waitcnt lgkmcnt(0)" ::: "memory");
        __builtin_amdgcn_sched_barrier(0);
        __builtin_amdgcn_s_setprio(1);
        #pragma unroll
        for (int mf = 0; mf < 4; ++mf)
            #pragma unroll
            for (int nf = 0; nf < 4; ++nf)
                acc[mf][nf] = __builtin_amdgcn_mfma_f32_16x16x32_f16(b1[nf], a1[mf], acc[mf][nf], 0, 0, 0);
        __builtin_amdgcn_s_setprio(0);
        __builtin_amdgcn_sched_barrier(0);

        // ---- tile gate: next tile resident; counted vmcnt, never 0 in steady state ----
        if (kt < NKT - 1) {
            if (kt < NKT - 2) asm volatile("s_waitcnt vmcnt(6)" ::: "memory");
            else              asm volatile("s_waitcnt vmcnt(0)" ::: "memory");
            __builtin_amdgcn_s_barrier();
            __builtin_amdgcn_sched_barrier(0);
        }
        cur = (cur == 2) ? 0 : cur + 1;
        nx2 = (nx2 == 2) ? 0 : nx2 + 1;
    }

    // ---- epilogue: bias + sigmoid -> f16, 8B vector stores ----
    // swapped layout: lane holds rows gm = mf*16+(lane&15), cols gn0..gn0+3
    #pragma unroll
    for (int nf = 0; nf < 4; ++nf) {
        int gn0 = bn * 128 + wc * 64 + nf * 16 + ((lane >> 4) << 2);
        f32x4 b4 = *(const f32x4*)(bias + gn0);
        #pragma unroll
        for (int mf = 0; mf < 4; ++mf) {
            int gm = bm * 256 + wr * 64 + mf * 16 + (lane & 15);
            f16x4 o;
            #pragma unroll
            for (int j = 0; j < 4; ++j) {
                float z = acc[mf][nf][j] + b4[j];
                o[j] = (f16)(1.0f / (1.0f + __expf(-z)));
            }
            *(f16x4*)(O + (size_t)gm * DIM + gn0) = o;
        }
    }
}

// ---------- output GEMV ----------
__global__ __launch_bounds__(256) void out_gemv(const f16* __restrict__ A,
                                                const float* __restrict__ Wout,
                                                const float* __restrict__ bout,
                                                float* __restrict__ out) {
    int wid  = threadIdx.x >> 6;
    int lane = threadIdx.x & 63;
    int row  = blockIdx.x * 4 + wid;
    const f16* p = A + (size_t)row * DIM + lane * 16;
    const float* pw = Wout + lane * 16;
    float s = 0.f;
    #pragma unroll
    for (int i = 0; i < 4; ++i) {
        f16x4 h4 = *(const f16x4*)(p + i * 4);
        float4 w4 = *(const float4*)(pw + i * 4);
        s += (float)h4.x * w4.x + (float)h4.y * w4.y + (float)h4.z * w4.z + (float)h4.w * w4.w;
    }
    #pragma unroll
    for (int off = 32; off > 0; off >>= 1)
        s += __shfl_down(s, off);
    if (lane == 0) out[row] = s + bout[0];
}

// ---------- launcher ----------
extern "C" void kernel_launch(void* const* d_in, const int* in_sizes, int n_in,
                              void* d_out, int out_size, void* d_ws, size_t ws_size,
                              hipStream_t stream) {
    const float* x    = (const float*)d_in[0];
    const float* W0   = (const float*)d_in[1];
    const float* b0   = (const float*)d_in[2];
    const float* Wh   = (const float*)d_in[3];
    const float* bh   = (const float*)d_in[4];
    const float* Wout = (const float*)d_in[5];
    const float* bout = (const float*)d_in[6];
    float* out = (float*)d_out;

    f16* ws = (f16*)d_ws;
    f16* Wf = ws;                                  // 10*1024*1024 f16 = 20 MB
    f16* A0 = Wf + (size_t)NLAYER * DIM * DIM;     // 8192*1024 f16 = 16 MB
    f16* A1 = A0 + (size_t)NROWS * DIM;            // 16 MB

    conv_weights<<<NLAYER * DIM * DIM / 1024, 256, 0, stream>>>(W0, Wh, Wf);
    conv_x<<<NROWS * DIM / 1024, 256, 0, stream>>>(x, A0);

    const f16* in = A0;
    f16* o = A1;
    for (int l = 0; l < NLAYER; ++l) {
        const float* bias = (l == 0) ? b0 : (bh + (size_t)(l - 1) * DIM);
        layer_gemm<<<256, 512, 0, stream>>>(in, Wf + (size_t)l * DIM * DIM, bias, o);
        f16* t = (f16*)in; in = o; o = t;
    }

    out_gemv<<<NROWS / 4, 256, 0, stream>>>(in, Wout, bout, out);
}